// Round 2
// baseline (43.126 us; speedup 1.0000x reference)
//
#include <hip/hip_runtime.h>

// LTI all-pass: cascade of 8 second-order all-pass sections in DF2T form.
//   per section: y = B2*x + s1 ; s1' = B1*(x-y) + s2 ; s2' = x - B2*y
// Cascade product = z^-16 A(1/z) / A(z) = B(z)/A(z) with b = a[::-1] (reference).
//
// Overlap-and-discard: mag <= sigmoid(1.3608)*0.99 = 0.7881 (hard bound from
// setup), so a 96-sample zero-state warm-up decays transients to ~1e-10.
// CHUNK=64 -> 131072 threads = 2048 waves = 2 waves/SIMD (8 waves/CU).

#define NROOTS 8
#define BATCH  32
#define TLEN   262144
#define CHUNK  64
#define WARM   96
#define CPR    (TLEN / CHUNK)   // 4096 chunks per row
#define GSAMP  16               // samples per prefetch group (4 x float4)

__global__ __launch_bounds__(256, 2) void allpass_kernel(
    const float* __restrict__ x,
    const float* __restrict__ mag_logits,
    const float* __restrict__ cos_logits,
    float* __restrict__ y)
{
    const int gid  = blockIdx.x * 256 + threadIdx.x;
    const int row  = gid >> 12;          // / 4096
    const int cidx = gid & 4095;

    float B1[NROOTS], B2[NROOTS], s1[NROOTS], s2[NROOTS];
#pragma unroll
    for (int s = 0; s < NROOTS; ++s) {
        float m = 0.99f / (1.0f + expf(-mag_logits[s]));
        float c = tanhf(cos_logits[s]);
        B1[s] = -2.0f * m * c;
        B2[s] = m * m;
        s1[s] = 0.0f; s2[s] = 0.0f;
    }

    auto step = [&](float v) -> float {
#pragma unroll
        for (int s = 0; s < NROOTS; ++s) {
            float o = fmaf(B2[s], v, s1[s]);
            s1[s] = fmaf(B1[s], v - o, s2[s]);
            s2[s] = fmaf(-B2[s], o, v);
            v = o;
        }
        return v;
    };

    const int t0     = cidx * CHUNK;
    // warm-up groups (16 samples each): 0 for chunk 0, clamped to available history
    const int warm_g = min(WARM / GSAMP, cidx * (CHUNK / GSAMP));   // 0, 4, or 6
    const int ng     = warm_g + CHUNK / GSAMP;                       // 4, 8, or 10 (even)

    const float4* pin  = reinterpret_cast<const float4*>(
        x + (size_t)row * TLEN + t0 - warm_g * GSAMP);
    float4*       pout = reinterpret_cast<float4*>(
        y + (size_t)row * TLEN + t0);

#define PROC4(vv) { vv.x = step(vv.x); vv.y = step(vv.y); vv.z = step(vv.z); vv.w = step(vv.w); }

    // Ping-pong prefetch: groups g (a*) and g+1 (b*) resident/in-flight.
    float4 a0, a1, a2, a3, b0, b1, b2_, b3;
    a0 = pin[0]; a1 = pin[1]; a2 = pin[2]; a3 = pin[3];         // group 0 (ng>=4 always)
    b0 = pin[4]; b1 = pin[5]; b2_ = pin[6]; b3 = pin[7];        // group 1

    for (int g = 0; g < ng; g += 2) {
        // ---- process group g (a), then immediately issue loads for g+2 ----
        PROC4(a0); PROC4(a1); PROC4(a2); PROC4(a3);
        if (g >= warm_g) {
            int o4 = (g - warm_g) * 4;
            pout[o4 + 0] = a0; pout[o4 + 1] = a1;
            pout[o4 + 2] = a2; pout[o4 + 3] = a3;
        }
        {
            int q = (g + 2 < ng) ? (g + 2) * 4 : 0;   // clamp: redundant in-bounds read
            a0 = pin[q]; a1 = pin[q + 1]; a2 = pin[q + 2]; a3 = pin[q + 3];
        }

        // ---- process group g+1 (b), then issue loads for g+3 ----
        PROC4(b0); PROC4(b1); PROC4(b2_); PROC4(b3);
        if (g + 1 >= warm_g) {
            int o4 = (g + 1 - warm_g) * 4;
            pout[o4 + 0] = b0; pout[o4 + 1] = b1;
            pout[o4 + 2] = b2_; pout[o4 + 3] = b3;
        }
        {
            int q = (g + 3 < ng) ? (g + 3) * 4 : 0;
            b0 = pin[q]; b1 = pin[q + 1]; b2_ = pin[q + 2]; b3 = pin[q + 3];
        }
    }
#undef PROC4
}

extern "C" void kernel_launch(void* const* d_in, const int* in_sizes, int n_in,
                              void* d_out, int out_size, void* d_ws, size_t ws_size,
                              hipStream_t stream) {
    const float* ex = (const float*)d_in[0];
    const float* ml = (const float*)d_in[1];
    const float* cl = (const float*)d_in[2];
    float* yo = (float*)d_out;

    const int total_threads = BATCH * CPR;      // 131072
    const int block = 256;
    allpass_kernel<<<total_threads / block, block, 0, stream>>>(ex, ml, cl, yo);
}